// Round 2
// baseline (711.010 us; speedup 1.0000x reference)
//
#include <hip/hip_runtime.h>
#include <hip/hip_bf16.h>
#include <math.h>

typedef __bf16 bf16_t;
typedef __attribute__((ext_vector_type(8))) __bf16 bx8;
typedef __attribute__((ext_vector_type(4))) __bf16 bx4;
typedef __attribute__((ext_vector_type(4))) float fx4;

#define DEV __device__ __forceinline__

// async global->LDS, 16B per lane. LDS dest is wave-uniform base (HW adds lane*16).
DEV void async_copy16(void* lds, const void* g) {
    __builtin_amdgcn_global_load_lds(
        (const __attribute__((address_space(1))) unsigned int*)g,
        (__attribute__((address_space(3))) unsigned int*)lds, 16, 0, 0);
}

// ---------------------------------------------------------------- convert
__global__ void __launch_bounds__(256) cvt_bf16(const float* __restrict__ in,
                                                bf16_t* __restrict__ out, int n) {
    int i = (blockIdx.x * 256 + threadIdx.x) * 4;
    if (i + 3 < n) {
        float4 v = *(const float4*)(in + i);
        bx4 o = { (__bf16)v.x, (__bf16)v.y, (__bf16)v.z, (__bf16)v.w };
        *(bx4*)(out + i) = o;
    }
}

// ---------------------------------------------------------------- GEMM C = A[MxK] * B[NxK]^T
// 128x128 tile, BK=32, 4 waves 2x2, 4x4 16x16x32 MFMA per wave.
// LDS rows hold 4 x 16B chunks; chunk g of row r stored at slot g ^ (r&3)
// (XOR swizzle: breaks the 8-way bank conflict of the 64B-row layout).
template <bool BF16_OUT>
__global__ void __launch_bounds__(256, 2) gemm_bt(const bf16_t* __restrict__ A,
                                                  const bf16_t* __restrict__ B,
                                                  void* __restrict__ C,
                                                  int M, int N, int K) {
    __shared__ bf16_t As[128 * 32];
    __shared__ bf16_t Bs[128 * 32];
    const int tid = threadIdx.x;
    const int w = tid >> 6, lane = tid & 63;
    const int ln = lane & 15, quad = lane >> 4;
    const int m0 = blockIdx.y * 128, n0 = blockIdx.x * 128;
    const int wm = (w >> 1) * 64, wn = (w & 1) * 64;

    fx4 acc[4][4];
#pragma unroll
    for (int i = 0; i < 4; ++i)
#pragma unroll
        for (int j = 0; j < 4; ++j) acc[i][j] = (fx4){0.f, 0.f, 0.f, 0.f};

    for (int k0 = 0; k0 < K; k0 += 32) {
#pragma unroll
        for (int call = 0; call < 2; ++call) {
            int c = w * 128 + call * 64 + lane;
            int row = c >> 2, g = (c & 3) ^ (row & 3);   // fetch swizzled chunk
            async_copy16(As + (size_t)(w * 128 + call * 64) * 8,
                         A + (size_t)(m0 + row) * K + k0 + g * 8);
            async_copy16(Bs + (size_t)(w * 128 + call * 64) * 8,
                         B + (size_t)(n0 + row) * K + k0 + g * 8);
        }
        __syncthreads();

        bx8 af[4], bf[4];
#pragma unroll
        for (int i = 0; i < 4; ++i)
            af[i] = *(const bx8*)(As + (size_t)(wm + i * 16 + ln) * 32 + (quad ^ (ln & 3)) * 8);
#pragma unroll
        for (int j = 0; j < 4; ++j)
            bf[j] = *(const bx8*)(Bs + (size_t)(wn + j * 16 + ln) * 32 + (quad ^ (ln & 3)) * 8);
#pragma unroll
        for (int i = 0; i < 4; ++i)
#pragma unroll
            for (int j = 0; j < 4; ++j)
                acc[i][j] = __builtin_amdgcn_mfma_f32_16x16x32_bf16(af[i], bf[j], acc[i][j], 0, 0, 0);
        __syncthreads();
    }

    // epilogue: C/D layout col=lane&15, row=quad*4+r (m89-verified)
#pragma unroll
    for (int i = 0; i < 4; ++i) {
        int mrow = m0 + wm + i * 16 + quad * 4;
#pragma unroll
        for (int j = 0; j < 4; ++j) {
            int ncol = n0 + wn + j * 16 + ln;
#pragma unroll
            for (int r = 0; r < 4; ++r) {
                if (BF16_OUT)
                    ((bf16_t*)C)[(size_t)(mrow + r) * N + ncol] = (__bf16)acc[i][j][r];
                else
                    ((float*)C)[(size_t)(mrow + r) * N + ncol] = acc[i][j][r];
            }
        }
    }
}

// ---------------------------------------------------------------- V transpose: [b,t,hd] -> [b,h,hd,t]
__global__ void __launch_bounds__(256) vtrans(const bf16_t* __restrict__ qkv,
                                              bf16_t* __restrict__ vt) {
    __shared__ bf16_t tile[64][65];
    const int tid = threadIdx.x;
    const int bh = blockIdx.z;
    const int b = bh >> 4, h = bh & 15;
    const int t0 = blockIdx.x * 64, hd0 = blockIdx.y * 64;
    const bf16_t* src = qkv + (size_t)(b * 2048 + t0) * 6144 + 4096 + h * 128 + hd0;
    const int rr = tid >> 6, cc = tid & 63;
#pragma unroll
    for (int i = 0; i < 16; ++i)
        tile[rr + i * 4][cc] = src[(size_t)(rr + i * 4) * 6144 + cc];
    __syncthreads();
    bf16_t* dst = vt + ((size_t)bh * 128 + hd0) * 2048 + t0;
#pragma unroll
    for (int i = 0; i < 16; ++i)
        dst[(size_t)(rr + i * 4) * 2048 + cc] = tile[cc][rr + i * 4];
}

// ---------------------------------------------------------------- flash attention
// grid: (qtile=16, bh=32). 4 waves; wave w: q rows [w*32, w*32+32).
// Ks/Vs 128x128 tiles; 16B chunk g of row r stored at LDS slot g ^ (r&15)
// (XOR swizzle — 256B rows otherwise put every row at bank 0 -> 16-way conflict).
// P (32x128/wave) aliases consumed Ks with the same chunk swizzle.
__global__ void __launch_bounds__(256, 2) attn(const bf16_t* __restrict__ qkv,
                                               const bf16_t* __restrict__ vt,
                                               bf16_t* __restrict__ y) {
    __shared__ bf16_t Ks[128 * 128];
    __shared__ bf16_t Vs[128 * 128];
    const int tid = threadIdx.x;
    const int w = tid >> 6, lane = tid & 63;
    const int ln = lane & 15, quad = lane >> 4;
    const int qt = blockIdx.x, bh = blockIdx.y;
    const int b = bh >> 4, h = bh & 15;
    const float CEXP = 0.08838834764831845f * 1.44269504088896340f;  // (1/sqrt(128))*log2(e)

    const bf16_t* Qb = qkv + (size_t)(b * 2048 + qt * 128) * 6144 + h * 128;
    const bf16_t* Kb = qkv + (size_t)(b * 2048) * 6144 + 2048 + h * 128;
    const bf16_t* Vb = vt + (size_t)bh * 128 * 2048;

    // Q A-fragments direct from global (A[m=lane&15][k=quad*8+j])
    bx8 qf[2][4];
#pragma unroll
    for (int i = 0; i < 2; ++i)
#pragma unroll
        for (int kk = 0; kk < 4; ++kk)
            qf[i][kk] = *(const bx8*)(Qb + (size_t)(w * 32 + i * 16 + ln) * 6144 + kk * 32 + quad * 8);

    fx4 o[2][8];
#pragma unroll
    for (int i = 0; i < 2; ++i)
#pragma unroll
        for (int j = 0; j < 8; ++j) o[i][j] = (fx4){0.f, 0.f, 0.f, 0.f};
    float mstate[2][4], lstate[2][4];
#pragma unroll
    for (int i = 0; i < 2; ++i)
#pragma unroll
        for (int r = 0; r < 4; ++r) { mstate[i][r] = -INFINITY; lstate[i][r] = 0.f; }

    for (int kt = 0; kt < 16; ++kt) {
#pragma unroll
        for (int call = 0; call < 8; ++call) {
            int c = w * 512 + call * 64 + lane;
            int row = c >> 4, g = (c & 15) ^ (row & 15);   // fetch swizzled chunk
            async_copy16(Ks + (size_t)(w * 512 + call * 64) * 8,
                         Kb + (size_t)(kt * 128 + row) * 6144 + g * 8);
            async_copy16(Vs + (size_t)(w * 512 + call * 64) * 8,
                         Vb + (size_t)row * 2048 + kt * 128 + g * 8);
        }
        __syncthreads();

        // S = Q K^T
        fx4 s[2][8];
#pragma unroll
        for (int i = 0; i < 2; ++i)
#pragma unroll
            for (int j = 0; j < 8; ++j) s[i][j] = (fx4){0.f, 0.f, 0.f, 0.f};
#pragma unroll
        for (int kk = 0; kk < 4; ++kk) {
            bx8 kf[8];
#pragma unroll
            for (int j = 0; j < 8; ++j)
                kf[j] = *(const bx8*)(Ks + (size_t)(j * 16 + ln) * 128 + ((kk * 4 + quad) ^ ln) * 8);
#pragma unroll
            for (int i = 0; i < 2; ++i)
#pragma unroll
                for (int j = 0; j < 8; ++j)
                    s[i][j] = __builtin_amdgcn_mfma_f32_16x16x32_bf16(qf[i][kk], kf[j], s[i][j], 0, 0, 0);
        }

        // online softmax (rows quad*4+r, cols j*16+ln; reduce across the 16 lanes of quad)
        float alpha[2][4];
#pragma unroll
        for (int i = 0; i < 2; ++i)
#pragma unroll
            for (int r = 0; r < 4; ++r) {
                float mx = s[i][0][r];
#pragma unroll
                for (int j = 1; j < 8; ++j) mx = fmaxf(mx, s[i][j][r]);
                mx = fmaxf(mx, __shfl_xor(mx, 1));
                mx = fmaxf(mx, __shfl_xor(mx, 2));
                mx = fmaxf(mx, __shfl_xor(mx, 4));
                mx = fmaxf(mx, __shfl_xor(mx, 8));
                float mn = fmaxf(mstate[i][r], mx);
                alpha[i][r] = exp2f((mstate[i][r] - mn) * CEXP);
                mstate[i][r] = mn;
            }
#pragma unroll
        for (int i = 0; i < 2; ++i)
#pragma unroll
            for (int j = 0; j < 8; ++j)
#pragma unroll
                for (int r = 0; r < 4; ++r)
                    s[i][j][r] = exp2f((s[i][j][r] - mstate[i][r]) * CEXP);
#pragma unroll
        for (int i = 0; i < 2; ++i)
#pragma unroll
            for (int r = 0; r < 4; ++r) {
                float sm = 0.f;
#pragma unroll
                for (int j = 0; j < 8; ++j) sm += s[i][j][r];
                sm += __shfl_xor(sm, 1);
                sm += __shfl_xor(sm, 2);
                sm += __shfl_xor(sm, 4);
                sm += __shfl_xor(sm, 8);
                lstate[i][r] = lstate[i][r] * alpha[i][r] + sm;
            }
#pragma unroll
        for (int i = 0; i < 2; ++i)
#pragma unroll
            for (int j = 0; j < 8; ++j)
#pragma unroll
                for (int r = 0; r < 4; ++r) o[i][j][r] *= alpha[i][r];

        __syncthreads();  // all waves done reading Ks before P overwrites it

        // P -> LDS (C-layout -> A-layout), chunk-swizzled in place
        bf16_t* Pw = Ks + w * 4096;
#pragma unroll
        for (int i = 0; i < 2; ++i)
#pragma unroll
            for (int j = 0; j < 8; ++j) {
                int cc = 2 * j + (ln >> 3);
#pragma unroll
                for (int r = 0; r < 4; ++r) {
                    int row = i * 16 + quad * 4 + r;
                    Pw[row * 128 + (cc ^ (row & 15)) * 8 + (ln & 7)] = (__bf16)s[i][j][r];
                }
            }

        // O += P V
#pragma unroll
        for (int kk = 0; kk < 4; ++kk) {
            bx8 pf[2], vf[8];
#pragma unroll
            for (int i = 0; i < 2; ++i)
                pf[i] = *(const bx8*)(Pw + (size_t)(i * 16 + ln) * 128 + ((kk * 4 + quad) ^ ln) * 8);
#pragma unroll
            for (int j = 0; j < 8; ++j)
                vf[j] = *(const bx8*)(Vs + (size_t)(j * 16 + ln) * 128 + ((kk * 4 + quad) ^ ln) * 8);
#pragma unroll
            for (int i = 0; i < 2; ++i)
#pragma unroll
                for (int j = 0; j < 8; ++j)
                    o[i][j] = __builtin_amdgcn_mfma_f32_16x16x32_bf16(pf[i], vf[j], o[i][j], 0, 0, 0);
        }
        __syncthreads();  // done with Vs & P before next stage
    }

    // epilogue: y[b,t,h*128+hd] bf16
#pragma unroll
    for (int i = 0; i < 2; ++i)
#pragma unroll
        for (int j = 0; j < 8; ++j)
#pragma unroll
            for (int r = 0; r < 4; ++r) {
                int t = qt * 128 + w * 32 + i * 16 + quad * 4 + r;
                int col = h * 128 + j * 16 + ln;
                y[(size_t)(b * 2048 + t) * 2048 + col] = (__bf16)(o[i][j][r] / lstate[i][r]);
            }
}

// ---------------------------------------------------------------- launch
extern "C" void kernel_launch(void* const* d_in, const int* in_sizes, int n_in,
                              void* d_out, int out_size, void* d_ws, size_t ws_size,
                              hipStream_t stream) {
    const float* x    = (const float*)d_in[0];
    const float* wqkv = (const float*)d_in[1];
    const float* wo   = (const float*)d_in[2];
    float* out = (float*)d_out;
    char* ws = (char*)d_ws;

    bf16_t* Xb  = (bf16_t*)(ws);                          // 16 MB (reused as Y)
    bf16_t* Wqb = (bf16_t*)(ws + (size_t)(16u << 20));    // 24 MB
    bf16_t* Wob = (bf16_t*)(ws + (size_t)(40u << 20));    //  8 MB
    bf16_t* QKV = (bf16_t*)(ws + (size_t)(48u << 20));    // 48 MB
    bf16_t* VT  = (bf16_t*)(ws + (size_t)(96u << 20));    // 16 MB
    bf16_t* Y   = Xb;

    cvt_bf16<<<8388608 / 1024, 256, 0, stream>>>(x, Xb, 8388608);
    cvt_bf16<<<12582912 / 1024, 256, 0, stream>>>(wqkv, Wqb, 12582912);
    cvt_bf16<<<4194304 / 1024, 256, 0, stream>>>(wo, Wob, 4194304);

    gemm_bt<true><<<dim3(48, 32), 256, 0, stream>>>(Xb, Wqb, QKV, 4096, 6144, 2048);
    vtrans<<<dim3(32, 2, 32), 256, 0, stream>>>(QKV, VT);
    attn<<<dim3(16, 32), 256, 0, stream>>>(QKV, VT, Y);
    gemm_bt<false><<<dim3(16, 32), 256, 0, stream>>>(Y, Wob, out, 4096, 2048, 2048);
}

// Round 3
// 693.855 us; speedup vs baseline: 1.0247x; 1.0247x over previous
//
#include <hip/hip_runtime.h>
#include <hip/hip_bf16.h>
#include <math.h>

typedef __bf16 bf16_t;
typedef __attribute__((ext_vector_type(8))) __bf16 bx8;
typedef __attribute__((ext_vector_type(4))) __bf16 bx4;
typedef __attribute__((ext_vector_type(4))) float fx4;

#define DEV __device__ __forceinline__

// async global->LDS, 16B per lane. Lane addresses MUST be linear (lane i ->
// base + i*16) or coalescing breaks (R2: 3x FETCH_SIZE). LDS layout == global
// layout; all swizzling is done by the PRODUCERS of the global buffers.
DEV void async_copy16(void* lds, const void* g) {
    __builtin_amdgcn_global_load_lds(
        (const __attribute__((address_space(1))) unsigned int*)g,
        (__attribute__((address_space(3))) unsigned int*)lds, 16, 0, 0);
}

// ---------------------------------------------------------------- convert + GEMM-input swizzle
// f32 -> bf16; rows of length 2048; 16B chunk g within each 32-elem group goes
// to slot g ^ ((row>>1)&3).  GEMM ds_read then hits 8 bank-quads 2-way (free).
__global__ void __launch_bounds__(256) cvt_swz(const float* __restrict__ in,
                                               bf16_t* __restrict__ out, int nchunks) {
    int c = blockIdx.x * 256 + threadIdx.x;
    if (c >= nchunks) return;
    int r = c >> 8;          // 256 chunks per 2048-row
    int k8 = c & 255;
    int grp = k8 >> 2, g = k8 & 3;
    float4 v0 = *(const float4*)(in + (size_t)c * 8);
    float4 v1 = *(const float4*)(in + (size_t)c * 8 + 4);
    bx8 o = {(__bf16)v0.x, (__bf16)v0.y, (__bf16)v0.z, (__bf16)v0.w,
             (__bf16)v1.x, (__bf16)v1.y, (__bf16)v1.z, (__bf16)v1.w};
    int gs = g ^ ((r >> 1) & 3);
    *(bx8*)(out + (size_t)r * 2048 + grp * 32 + gs * 8) = o;
}

// ---------------------------------------------------------------- GEMM C = A[MxK] * B[NxK]^T
// A,B stored pre-swizzled (cvt_swz layout). Fetch is linear; ds_read slot =
// quad ^ ((ln>>1)&3). Epilogue optionally writes the attention-K swizzle
// (chunk ^ (t&15) within 128-col heads) for output cols [klo, khi).
template <bool BF16_OUT>
__global__ void __launch_bounds__(256, 2) gemm_bt(const bf16_t* __restrict__ A,
                                                  const bf16_t* __restrict__ B,
                                                  void* __restrict__ C,
                                                  int M, int N, int K,
                                                  int klo, int khi) {
    __shared__ bf16_t As[128 * 32];
    __shared__ bf16_t Bs[128 * 32];
    const int tid = threadIdx.x;
    const int w = tid >> 6, lane = tid & 63;
    const int ln = lane & 15, quad = lane >> 4;
    const int m0 = blockIdx.y * 128, n0 = blockIdx.x * 128;
    const int wm = (w >> 1) * 64, wn = (w & 1) * 64;
    const bool kswz = (n0 >= klo) && (n0 < khi);

    fx4 acc[4][4];
#pragma unroll
    for (int i = 0; i < 4; ++i)
#pragma unroll
        for (int j = 0; j < 4; ++j) acc[i][j] = (fx4){0.f, 0.f, 0.f, 0.f};

    const int slot = quad ^ ((ln >> 1) & 3);

    for (int k0 = 0; k0 < K; k0 += 32) {
#pragma unroll
        for (int call = 0; call < 2; ++call) {
            int c = w * 128 + call * 64 + lane;
            int row = c >> 2, g = c & 3;            // LINEAR fetch
            async_copy16(As + (size_t)(w * 128 + call * 64) * 8,
                         A + (size_t)(m0 + row) * K + k0 + g * 8);
            async_copy16(Bs + (size_t)(w * 128 + call * 64) * 8,
                         B + (size_t)(n0 + row) * K + k0 + g * 8);
        }
        __syncthreads();

        bx8 af[4], bf[4];
#pragma unroll
        for (int i = 0; i < 4; ++i)
            af[i] = *(const bx8*)(As + (size_t)(wm + i * 16 + ln) * 32 + slot * 8);
#pragma unroll
        for (int j = 0; j < 4; ++j)
            bf[j] = *(const bx8*)(Bs + (size_t)(wn + j * 16 + ln) * 32 + slot * 8);
#pragma unroll
        for (int i = 0; i < 4; ++i)
#pragma unroll
            for (int j = 0; j < 4; ++j)
                acc[i][j] = __builtin_amdgcn_mfma_f32_16x16x32_bf16(af[i], bf[j], acc[i][j], 0, 0, 0);
        __syncthreads();
    }

    // epilogue: C/D layout col=lane&15, row=quad*4+r
#pragma unroll
    for (int i = 0; i < 4; ++i) {
        int mrow = m0 + wm + i * 16 + quad * 4;
#pragma unroll
        for (int j = 0; j < 4; ++j) {
            int ncol = n0 + wn + j * 16 + ln;
#pragma unroll
            for (int r = 0; r < 4; ++r) {
                int row = mrow + r;
                int col = ncol;
                if (kswz) {  // attention-K swizzle within this head's 128 cols
                    int dh = ncol & 127;
                    col = (ncol & ~127) + (((dh >> 3) ^ (row & 15)) * 8) + (dh & 7);
                }
                if (BF16_OUT)
                    ((bf16_t*)C)[(size_t)row * N + col] = (__bf16)acc[i][j][r];
                else
                    ((float*)C)[(size_t)row * N + col] = acc[i][j][r];
            }
        }
    }
}

// ---------------------------------------------------------------- V transpose: [b,t,hd] -> [b,h,hd,t]
// writes VT pre-swizzled: t-chunk g within each 128-t tile at slot g ^ (hd&15)
__global__ void __launch_bounds__(256) vtrans(const bf16_t* __restrict__ qkv,
                                              bf16_t* __restrict__ vt) {
    __shared__ bf16_t tile[64][65];
    const int tid = threadIdx.x;
    const int bh = blockIdx.z;
    const int b = bh >> 4, h = bh & 15;
    const int t0 = blockIdx.x * 64, hd0 = blockIdx.y * 64;
    const bf16_t* src = qkv + (size_t)(b * 2048 + t0) * 6144 + 4096 + h * 128 + hd0;
    const int rr = tid >> 6, cc = tid & 63;
#pragma unroll
    for (int i = 0; i < 16; ++i)
        tile[rr + i * 4][cc] = src[(size_t)(rr + i * 4) * 6144 + cc];
    __syncthreads();
    bf16_t* dst = vt + (size_t)bh * 128 * 2048;
    int tt = t0 + cc;
#pragma unroll
    for (int i = 0; i < 16; ++i) {
        int hd = hd0 + rr + i * 4;
        int tsw = (tt & ~127) + ((((tt >> 3) & 15) ^ (hd & 15)) * 8) + (tt & 7);
        dst[(size_t)hd * 2048 + tsw] = tile[cc][rr + i * 4];
    }
}

// ---------------------------------------------------------------- flash attention
// grid: (qtile=16, bh=32). 4 waves; wave w: q rows [w*32, w*32+32).
// K/V arrive pre-swizzled in global (chunk g of row r at slot g ^ (r&15)),
// fetched LINEARLY into LDS -> conflict-free ds_reads with slot ^ ln.
// P aliases consumed Ks with the same swizzle (plain ds_write, key row&15).
// Epilogue writes Y pre-swizzled for the output-projection GEMM.
__global__ void __launch_bounds__(256, 2) attn(const bf16_t* __restrict__ qkv,
                                               const bf16_t* __restrict__ vt,
                                               bf16_t* __restrict__ y) {
    __shared__ bf16_t Ks[128 * 128];
    __shared__ bf16_t Vs[128 * 128];
    const int tid = threadIdx.x;
    const int w = tid >> 6, lane = tid & 63;
    const int ln = lane & 15, quad = lane >> 4;
    const int qt = blockIdx.x, bh = blockIdx.y;
    const int b = bh >> 4, h = bh & 15;
    const float CEXP = 0.08838834764831845f * 1.44269504088896340f;  // (1/sqrt(128))*log2(e)

    const bf16_t* Qb = qkv + (size_t)(b * 2048 + qt * 128) * 6144 + h * 128;
    const bf16_t* Kb = qkv + (size_t)(b * 2048) * 6144 + 2048 + h * 128;
    const bf16_t* Vb = vt + (size_t)bh * 128 * 2048;

    // Q A-fragments direct from global (Q region is unswizzled)
    bx8 qf[2][4];
#pragma unroll
    for (int i = 0; i < 2; ++i)
#pragma unroll
        for (int kk = 0; kk < 4; ++kk)
            qf[i][kk] = *(const bx8*)(Qb + (size_t)(w * 32 + i * 16 + ln) * 6144 + kk * 32 + quad * 8);

    fx4 o[2][8];
#pragma unroll
    for (int i = 0; i < 2; ++i)
#pragma unroll
        for (int j = 0; j < 8; ++j) o[i][j] = (fx4){0.f, 0.f, 0.f, 0.f};
    float mstate[2][4], lstate[2][4];
#pragma unroll
    for (int i = 0; i < 2; ++i)
#pragma unroll
        for (int r = 0; r < 4; ++r) { mstate[i][r] = -INFINITY; lstate[i][r] = 0.f; }

    for (int kt = 0; kt < 16; ++kt) {
#pragma unroll
        for (int call = 0; call < 8; ++call) {
            int c = w * 512 + call * 64 + lane;
            int row = c >> 4, g = c & 15;            // LINEAR fetch
            async_copy16(Ks + (size_t)(w * 512 + call * 64) * 8,
                         Kb + (size_t)(kt * 128 + row) * 6144 + g * 8);
            async_copy16(Vs + (size_t)(w * 512 + call * 64) * 8,
                         Vb + (size_t)row * 2048 + kt * 128 + g * 8);
        }
        __syncthreads();

        // S = Q K^T
        fx4 s[2][8];
#pragma unroll
        for (int i = 0; i < 2; ++i)
#pragma unroll
            for (int j = 0; j < 8; ++j) s[i][j] = (fx4){0.f, 0.f, 0.f, 0.f};
#pragma unroll
        for (int kk = 0; kk < 4; ++kk) {
            bx8 kf[8];
#pragma unroll
            for (int j = 0; j < 8; ++j)
                kf[j] = *(const bx8*)(Ks + (size_t)(j * 16 + ln) * 128 + ((kk * 4 + quad) ^ ln) * 8);
#pragma unroll
            for (int i = 0; i < 2; ++i)
#pragma unroll
                for (int j = 0; j < 8; ++j)
                    s[i][j] = __builtin_amdgcn_mfma_f32_16x16x32_bf16(qf[i][kk], kf[j], s[i][j], 0, 0, 0);
        }

        // online softmax (rows quad*4+r, cols j*16+ln; reduce across the 16 lanes of quad)
        float alpha[2][4];
#pragma unroll
        for (int i = 0; i < 2; ++i)
#pragma unroll
            for (int r = 0; r < 4; ++r) {
                float mx = s[i][0][r];
#pragma unroll
                for (int j = 1; j < 8; ++j) mx = fmaxf(mx, s[i][j][r]);
                mx = fmaxf(mx, __shfl_xor(mx, 1));
                mx = fmaxf(mx, __shfl_xor(mx, 2));
                mx = fmaxf(mx, __shfl_xor(mx, 4));
                mx = fmaxf(mx, __shfl_xor(mx, 8));
                float mn = fmaxf(mstate[i][r], mx);
                alpha[i][r] = exp2f((mstate[i][r] - mn) * CEXP);
                mstate[i][r] = mn;
            }
#pragma unroll
        for (int i = 0; i < 2; ++i)
#pragma unroll
            for (int j = 0; j < 8; ++j)
#pragma unroll
                for (int r = 0; r < 4; ++r)
                    s[i][j][r] = exp2f((s[i][j][r] - mstate[i][r]) * CEXP);
#pragma unroll
        for (int i = 0; i < 2; ++i)
#pragma unroll
            for (int r = 0; r < 4; ++r) {
                float sm = 0.f;
#pragma unroll
                for (int j = 0; j < 8; ++j) sm += s[i][j][r];
                sm += __shfl_xor(sm, 1);
                sm += __shfl_xor(sm, 2);
                sm += __shfl_xor(sm, 4);
                sm += __shfl_xor(sm, 8);
                lstate[i][r] = lstate[i][r] * alpha[i][r] + sm;
            }
#pragma unroll
        for (int i = 0; i < 2; ++i)
#pragma unroll
            for (int j = 0; j < 8; ++j)
#pragma unroll
                for (int r = 0; r < 4; ++r) o[i][j][r] *= alpha[i][r];

        __syncthreads();  // all waves done reading Ks before P overwrites it

        // P -> LDS (C-layout -> A-layout), chunk-swizzled, wave-private region
        bf16_t* Pw = Ks + w * 4096;
#pragma unroll
        for (int i = 0; i < 2; ++i)
#pragma unroll
            for (int j = 0; j < 8; ++j) {
                int cc = 2 * j + (ln >> 3);
#pragma unroll
                for (int r = 0; r < 4; ++r) {
                    int row = i * 16 + quad * 4 + r;
                    Pw[row * 128 + ((cc ^ (row & 15)) * 8) + (ln & 7)] = (__bf16)s[i][j][r];
                }
            }

        // O += P V
#pragma unroll
        for (int kk = 0; kk < 4; ++kk) {
            bx8 pf[2], vf[8];
#pragma unroll
            for (int i = 0; i < 2; ++i)
                pf[i] = *(const bx8*)(Pw + (size_t)(i * 16 + ln) * 128 + ((kk * 4 + quad) ^ ln) * 8);
#pragma unroll
            for (int j = 0; j < 8; ++j)
                vf[j] = *(const bx8*)(Vs + (size_t)(j * 16 + ln) * 128 + ((kk * 4 + quad) ^ ln) * 8);
#pragma unroll
            for (int i = 0; i < 2; ++i)
#pragma unroll
                for (int j = 0; j < 8; ++j)
                    o[i][j] = __builtin_amdgcn_mfma_f32_16x16x32_bf16(pf[i], vf[j], o[i][j], 0, 0, 0);
        }
        __syncthreads();  // done with Vs & P before next stage
    }

    // epilogue: y[t][col], pre-swizzled for GEMM2-A (chunk ^ ((t>>1)&3) in 32-col groups)
#pragma unroll
    for (int i = 0; i < 2; ++i)
#pragma unroll
        for (int j = 0; j < 8; ++j)
#pragma unroll
            for (int r = 0; r < 4; ++r) {
                int t = qt * 128 + w * 32 + i * 16 + quad * 4 + r;
                int col = h * 128 + j * 16 + ln;
                int csw = (col & ~31) + ((((col >> 3) & 3) ^ ((t >> 1) & 3)) * 8) + (col & 7);
                y[(size_t)(b * 2048 + t) * 2048 + csw] = (__bf16)(o[i][j][r] / lstate[i][r]);
            }
}

// ---------------------------------------------------------------- launch
extern "C" void kernel_launch(void* const* d_in, const int* in_sizes, int n_in,
                              void* d_out, int out_size, void* d_ws, size_t ws_size,
                              hipStream_t stream) {
    const float* x    = (const float*)d_in[0];
    const float* wqkv = (const float*)d_in[1];
    const float* wo   = (const float*)d_in[2];
    float* out = (float*)d_out;
    char* ws = (char*)d_ws;

    bf16_t* Xb  = (bf16_t*)(ws);                          // 16 MB (reused as Y)
    bf16_t* Wqb = (bf16_t*)(ws + (size_t)(16u << 20));    // 24 MB
    bf16_t* Wob = (bf16_t*)(ws + (size_t)(40u << 20));    //  8 MB
    bf16_t* QKV = (bf16_t*)(ws + (size_t)(48u << 20));    // 48 MB
    bf16_t* VT  = (bf16_t*)(ws + (size_t)(96u << 20));    // 16 MB
    bf16_t* Y   = Xb;

    cvt_swz<<<1048576 / 256, 256, 0, stream>>>(x, Xb, 1048576);
    cvt_swz<<<1572864 / 256, 256, 0, stream>>>(wqkv, Wqb, 1572864);
    cvt_swz<<<524288 / 256, 256, 0, stream>>>(wo, Wob, 524288);

    // QKV = X * Wqkv^T; K-region (cols 2048..4095) written attention-swizzled
    gemm_bt<true><<<dim3(48, 32), 256, 0, stream>>>(Xb, Wqb, QKV, 4096, 6144, 2048, 2048, 4096);
    vtrans<<<dim3(32, 2, 32), 256, 0, stream>>>(QKV, VT);
    attn<<<dim3(16, 32), 256, 0, stream>>>(QKV, VT, Y);
    gemm_bt<false><<<dim3(16, 32), 256, 0, stream>>>(Y, Wob, out, 4096, 2048, 2048, 0, 0);
}